// Round 1
// 345.305 us; speedup vs baseline: 1.0273x; 1.0273x over previous
//
#include <hip/hip_runtime.h>

#define HID 64
#define NCLS 16
#define NCENT 3
#define NCENTS (NCLS * NCENT)
#define BSHIFT 9               // 512 nodes per bin
#define BINW (1 << BSHIFT)
#define NBINMAX 256            // supports N <= 131072
#define CHUNK 4096             // edges per k_bin/k_count block
#define EPT (CHUNK / 256)
#define NU 8                   // k_agg gather pipeline depth
                               // (measured optimum: NU=16 regressed -4% via
                               //  VGPR->occupancy loss; NU=8 is the sweet spot)

static inline int ceil_div(int a, int b) { return (a + b - 1) / b; }

__device__ inline unsigned short f2bf(float f) {   // round-to-nearest-even
    unsigned int u = __float_as_uint(f);
    return (unsigned short)((u + 0x7FFFu + ((u >> 16) & 1u)) >> 16);
}
__device__ inline unsigned int pack2bf(float lo, float hi) {
    return (unsigned int)f2bf(lo) | ((unsigned int)f2bf(hi) << 16);
}
__device__ inline float bf2f(unsigned short h) {
    return __uint_as_float(((unsigned int)h) << 16);
}
__device__ inline float bflo(unsigned int u) { return __uint_as_float(u << 16); }
__device__ inline float bfhi(unsigned int u) { return __uint_as_float(u & 0xFFFF0000u); }

// ---- edge binning (counting-sort by dst>>BSHIFT) ------------------------

__global__ void k_count(const int* __restrict__ dst, int* __restrict__ binCnt,
                        int E, int nbins) {
    __shared__ int c[NBINMAX];
    for (int i = threadIdx.x; i < nbins; i += 256) c[i] = 0;
    __syncthreads();
    int e = blockIdx.x * CHUNK + threadIdx.x;
#pragma unroll
    for (int j = 0; j < EPT; j++, e += 256)
        if (e < E) atomicAdd(&c[dst[e] >> BSHIFT], 1);
    __syncthreads();
    for (int i = threadIdx.x; i < nbins; i += 256)
        if (c[i] > 0) atomicAdd(&binCnt[i], c[i]);
}

__global__ void k_binoff(const int* __restrict__ binCnt, int* __restrict__ binBase,
                         int nbins, int E) {
    __shared__ int ts[NBINMAX];
    int t = threadIdx.x;
    int v = (t < nbins) ? binCnt[t] : 0;
    ts[t] = v;
    __syncthreads();
    for (int off = 1; off < NBINMAX; off <<= 1) {
        int x = (t >= off) ? ts[t - off] : 0;
        __syncthreads();
        ts[t] += x;
        __syncthreads();
    }
    if (t < nbins) binBase[t] = ts[t] - v;   // exclusive
    if (t == 0) binBase[nbins] = E;
}

// Stage CHUNK edges in LDS packed by bin; copy out contiguous per-bin segments.
__global__ __launch_bounds__(256) void k_bin(const int* __restrict__ src,
                                             const int* __restrict__ dst,
                                             const int* __restrict__ binBase,
                                             int* __restrict__ binCur,
                                             int2* __restrict__ binned,
                                             int E, int nbins) {
    __shared__ int cnt[NBINMAX], off[NBINMAX], gbase[NBINMAX];
    __shared__ int2 stage[CHUNK];
    const int c0 = blockIdx.x * CHUNK;
    const int tid = threadIdx.x;
    cnt[tid] = 0;
    __syncthreads();
    int sv[EPT], dv[EPT];
#pragma unroll
    for (int j = 0; j < EPT; j++) {
        int e = c0 + j * 256 + tid;
        dv[j] = -1;
        if (e < E) {
            sv[j] = src[e];
            dv[j] = dst[e];
            atomicAdd(&cnt[dv[j] >> BSHIFT], 1);
        }
    }
    __syncthreads();
    off[tid] = cnt[tid];
    __syncthreads();
    for (int o = 1; o < NBINMAX; o <<= 1) {
        int x = (tid >= o) ? off[tid - o] : 0;
        __syncthreads();
        off[tid] += x;
        __syncthreads();
    }
    int excl = off[tid] - cnt[tid];
    __syncthreads();
    off[tid] = excl;
    gbase[tid] = (tid < nbins && cnt[tid] > 0) ? atomicAdd(&binCur[tid], cnt[tid]) : 0;
    cnt[tid] = 0;  // reuse as local cursor
    __syncthreads();
#pragma unroll
    for (int j = 0; j < EPT; j++)
        if (dv[j] >= 0) {
            int b = dv[j] >> BSHIFT;
            int pos = off[b] + atomicAdd(&cnt[b], 1);
            stage[pos] = make_int2(sv[j], dv[j]);
        }
    __syncthreads();
    int tot = min(CHUNK, E - c0);
    for (int i = tid; i < tot; i += 256) {
        int2 v = stage[i];
        int b = v.y >> BSHIFT;
        binned[binBase[b] + gbase[b] + (i - off[b])] = v;
    }
}

// One block per bin: fused hist + local scan + deg/rs/dinv write + col scatter.
__global__ __launch_bounds__(256) void k_fillc2(const int2* __restrict__ binned,
                                                const int* __restrict__ binBase,
                                                int* __restrict__ col,
                                                int* __restrict__ rs_out,
                                                int* __restrict__ deg_out,
                                                float* __restrict__ dinv_out, int N) {
    __shared__ int c[BINW];      // histogram, then cursor
    __shared__ int rsl[BINW];    // per-node row start
    __shared__ int ts[256];
    int b = blockIdx.x;
    int s = binBase[b], e = binBase[b + 1];
    int n0 = b << BSHIFT;
    int t = threadIdx.x;
    c[2 * t] = 0; c[2 * t + 1] = 0;
    __syncthreads();
    for (int i = s + t; i < e; i += 256)
        atomicAdd(&c[binned[i].y - n0], 1);
    __syncthreads();
    int v0 = c[2 * t], v1 = c[2 * t + 1];
    ts[t] = v0 + v1;
    __syncthreads();
    for (int off = 1; off < 256; off <<= 1) {
        int x = (t >= off) ? ts[t - off] : 0;
        __syncthreads();
        ts[t] += x;
        __syncthreads();
    }
    int base = binBase[b] + ts[t] - (v0 + v1);  // exclusive over node pairs
    rsl[2 * t] = base;
    rsl[2 * t + 1] = base + v0;
    int n = n0 + 2 * t;
    if (n < N) {
        deg_out[n] = v0; rs_out[n] = base;
        dinv_out[n] = rsqrtf((float)(v0 + 1));   // +1 self loop
    }
    if (n + 1 < N) {
        deg_out[n + 1] = v1; rs_out[n + 1] = base + v0;
        dinv_out[n + 1] = rsqrtf((float)(v1 + 1));
    }
    c[2 * t] = 0; c[2 * t + 1] = 0;   // reset as cursor
    __syncthreads();
    for (int i = s + t; i < e; i += 256) {
        int2 v = binned[i];
        int lo = v.y - n0;
        int pos = rsl[lo] + atomicAdd(&c[lo], 1);
        col[pos] = v.x;
    }
}

// ---- dense GEMM: out[N,64] = dinv[row] * (A[N,K] @ W[K,64]), bf16 out ----
// BF=false: fp32 input (layer 1, K=128). BF=true: bf16 input (layers 2,3).
// The dinv pre-scale turns the gather table into Atilde[i] = dinv[i]*h[i],
// so k_agg needs NO per-edge dinv gather (symmetric norm factors out).

template <int K, bool BF>
__global__ __launch_bounds__(256) void k_gemm(const void* __restrict__ Ain,
                                              const float* __restrict__ W,
                                              unsigned short* __restrict__ out,
                                              const float* __restrict__ dinv, int N) {
    __shared__ float Ws[64 * HID];
    __shared__ float As[64][68];
    const int tx = threadIdx.x & 15;
    const int ty = threadIdx.x >> 4;
    const int row0 = blockIdx.x * 64;

    float acc[4][4] = {};

    for (int k0 = 0; k0 < K; k0 += 64) {
        if (k0 > 0) __syncthreads();
        for (int i = threadIdx.x; i < 64 * 16; i += 256)
            ((float4*)Ws)[i] = ((const float4*)(W + (size_t)k0 * HID))[i];
        for (int i = threadIdx.x; i < 64 * 16; i += 256) {
            int r = i >> 4, c = i & 15;
            int row = row0 + r;
            float4 v = {0.f, 0.f, 0.f, 0.f};
            if (row < N) {
                if (BF) {
                    ushort4 u = *(const ushort4*)((const unsigned short*)Ain +
                                                  (size_t)row * K + k0 + 4 * c);
                    v.x = bf2f(u.x); v.y = bf2f(u.y); v.z = bf2f(u.z); v.w = bf2f(u.w);
                } else {
                    v = *(const float4*)((const float*)Ain + (size_t)row * K + k0 + 4 * c);
                }
            }
            *(float4*)&As[r][4 * c] = v;
        }
        __syncthreads();
#pragma unroll 4
        for (int k = 0; k < 64; k++) {
            float4 w = *(const float4*)&Ws[k * HID + 4 * tx];
#pragma unroll
            for (int i = 0; i < 4; i++) {
                float a = As[4 * ty + i][k];
                acc[i][0] = fmaf(a, w.x, acc[i][0]);
                acc[i][1] = fmaf(a, w.y, acc[i][1]);
                acc[i][2] = fmaf(a, w.z, acc[i][2]);
                acc[i][3] = fmaf(a, w.w, acc[i][3]);
            }
        }
    }
#pragma unroll
    for (int i = 0; i < 4; i++) {
        int row = row0 + 4 * ty + i;
        if (row < N) {
            float d = dinv[row];
            ushort4 v = {f2bf(d * acc[i][0]), f2bf(d * acc[i][1]),
                         f2bf(d * acc[i][2]), f2bf(d * acc[i][3])};
            *(ushort4*)&out[(size_t)row * HID + 4 * tx] = v;
        }
    }
}

// ---- aggregation: 8-lane group per node, lane = 8 feats (uint4 = 16B) ----
// Table rows are pre-scaled by dinv[src] in the GEMM epilogue, so the inner
// loop is a PURE SUM of gathered rows: no per-edge dinv gather, no per-edge
// multiply, no per-element tail mask. The clamped tail index repeats
// col[last]; we subtract pad copies of that row once after the loop.
// Final epilogue: out = relu(dinv[node]*acc + bias).

__global__ void k_agg(const unsigned short* __restrict__ tin,
                      unsigned short* __restrict__ out,
                      const int* __restrict__ rs, const int* __restrict__ deg,
                      const int* __restrict__ col,
                      const float* __restrict__ dinv, const float* __restrict__ bias,
                      int N, int relu) {
    int node = (blockIdx.x * blockDim.x + threadIdx.x) >> 3;
    int l = threadIdx.x & 7;
    if (node >= N) return;
    float di = dinv[node];
    // self loop: Atilde[node] = dinv[node]*h[node]; total self term di^2*h. ✓
    uint4 tb = ((const uint4*)(tin + (size_t)node * HID))[l];
    float a0 = bflo(tb.x), a1 = bfhi(tb.x);
    float a2 = bflo(tb.y), a3 = bfhi(tb.y);
    float a4 = bflo(tb.z), a5 = bfhi(tb.z);
    float a6 = bflo(tb.w), a7 = bfhi(tb.w);

    int beg = rs[node];
    int cnt = deg[node];
    int last = beg + cnt - 1;
    for (int e = 0; e < cnt; e += NU) {
        int sv[NU];
#pragma unroll
        for (int j = 0; j < NU; j++) {
            int idx = beg + e + j;
            sv[j] = col[idx < last ? idx : last];
        }
        uint4 vv[NU];
#pragma unroll
        for (int j = 0; j < NU; j++) vv[j] = ((const uint4*)(tin + (size_t)sv[j] * HID))[l];
#pragma unroll
        for (int j = 0; j < NU; j++) {
            a0 += bflo(vv[j].x); a1 += bfhi(vv[j].x);
            a2 += bflo(vv[j].y); a3 += bfhi(vv[j].y);
            a4 += bflo(vv[j].z); a5 += bfhi(vv[j].z);
            a6 += bflo(vv[j].w); a7 += bfhi(vv[j].w);
        }
    }
    // tail correction: padded slots each added Atilde[col[last]] once
    int pad = (NU - (cnt & (NU - 1))) & (NU - 1);
    if (cnt > 0 && pad > 0) {
        float fp = (float)pad;
        uint4 vl = ((const uint4*)(tin + (size_t)col[last] * HID))[l];  // L1 hit
        a0 = fmaf(-fp, bflo(vl.x), a0); a1 = fmaf(-fp, bfhi(vl.x), a1);
        a2 = fmaf(-fp, bflo(vl.y), a2); a3 = fmaf(-fp, bfhi(vl.y), a3);
        a4 = fmaf(-fp, bflo(vl.z), a4); a5 = fmaf(-fp, bfhi(vl.z), a5);
        a6 = fmaf(-fp, bflo(vl.w), a6); a7 = fmaf(-fp, bfhi(vl.w), a7);
    }
    float4 b0 = ((const float4*)bias)[2 * l];
    float4 b1 = ((const float4*)bias)[2 * l + 1];
    a0 = fmaf(di, a0, b0.x); a1 = fmaf(di, a1, b0.y);
    a2 = fmaf(di, a2, b0.z); a3 = fmaf(di, a3, b0.w);
    a4 = fmaf(di, a4, b1.x); a5 = fmaf(di, a5, b1.y);
    a6 = fmaf(di, a6, b1.z); a7 = fmaf(di, a7, b1.w);
    if (relu) {
        a0 = fmaxf(a0, 0.f); a1 = fmaxf(a1, 0.f); a2 = fmaxf(a2, 0.f); a3 = fmaxf(a3, 0.f);
        a4 = fmaxf(a4, 0.f); a5 = fmaxf(a5, 0.f); a6 = fmaxf(a6, 0.f); a7 = fmaxf(a7, 0.f);
    }
    uint4 o;
    o.x = pack2bf(a0, a1); o.y = pack2bf(a2, a3);
    o.z = pack2bf(a4, a5); o.w = pack2bf(a6, a7);
    ((uint4*)(out + (size_t)node * HID))[l] = o;
}

// ---- fused mean-pool + centroid-distance head (bf16 input) --------------

__global__ void k_pool_head(const unsigned short* __restrict__ h,
                            const int* __restrict__ batch,
                            const float* __restrict__ cent, const float* __restrict__ rbias,
                            float* __restrict__ out, int N) {
    int g = blockIdx.x;
    int lo = 0, hi = N;
    while (lo < hi) { int mid = (lo + hi) >> 1; if (batch[mid] < g) lo = mid + 1; else hi = mid; }
    int s = lo;
    lo = 0; hi = N;
    while (lo < hi) { int mid = (lo + hi) >> 1; if (batch[mid] < g + 1) lo = mid + 1; else hi = mid; }
    int e = lo;

    __shared__ float part[4][HID];
    __shared__ float embS[HID];
    __shared__ float dS[NCENTS];
    __shared__ float dpcS[NCLS];

    int lane = threadIdx.x & 63, wid = threadIdx.x >> 6;
    float acc = 0.0f;
    for (int i = s + wid; i < e; i += 4) acc += bf2f(h[(size_t)i * HID + lane]);
    part[wid][lane] = acc;
    __syncthreads();
    if (wid == 0) {
        float v = part[0][lane] + part[1][lane] + part[2][lane] + part[3][lane];
        embS[lane] = v / fmaxf((float)(e - s), 1.0f);
    }
    __syncthreads();
    if (threadIdx.x < NCENTS) {
        const float* c = cent + threadIdx.x * HID;
        float d = 0.0f;
        for (int k = 0; k < HID; k++) { float df = embS[k] - c[k]; d = fmaf(df, df, d); }
        dS[threadIdx.x] = d;
    }
    __syncthreads();
    if (threadIdx.x < NCLS) {
        float m = fminf(dS[threadIdx.x * 3],
                        fminf(dS[threadIdx.x * 3 + 1], dS[threadIdx.x * 3 + 2]));
        dpcS[threadIdx.x] = m;
        out[g * (NCLS + 1) + threadIdx.x] = -m;
    }
    __syncthreads();
    if (threadIdx.x == 0) {
        float m = dpcS[0];
        for (int i = 1; i < NCLS; i++) m = fminf(m, dpcS[i]);
        out[g * (NCLS + 1) + NCLS] = m - rbias[0];
    }
}

// ---- launch -------------------------------------------------------------

extern "C" void kernel_launch(void* const* d_in, const int* in_sizes, int n_in,
                              void* d_out, int out_size, void* d_ws, size_t ws_size,
                              hipStream_t stream) {
    const float* x    = (const float*)d_in[0];
    const int*   ei   = (const int*)d_in[1];   // [2, E]: row0 = src, row1 = dst
    const int*   bat  = (const int*)d_in[2];
    const float* W1   = (const float*)d_in[3];
    const float* b1   = (const float*)d_in[4];
    const float* W2   = (const float*)d_in[5];
    const float* b2   = (const float*)d_in[6];
    const float* W3   = (const float*)d_in[7];
    const float* b3   = (const float*)d_in[8];
    const float* cent = (const float*)d_in[9];
    const float* rb   = (const float*)d_in[10];
    float* out = (float*)d_out;

    const int N = in_sizes[0] / 128;
    const int E = in_sizes[1] / 2;
    const int nbins = (N + BINW - 1) >> BSHIFT;

    char* p = (char*)d_ws;
    unsigned short* A  = (unsigned short*)p; p += (size_t)N * HID * 2;  // bf16 gather table (dinv-prescaled)
    unsigned short* Bb = (unsigned short*)p; p += (size_t)N * HID * 2;  // bf16 agg output
    int2*  binned = (int2*)p;  p += (size_t)E * 8;
    int*   col    = (int*)p;   p += (size_t)E * 4;
    float* dinv   = (float*)p; p += (size_t)N * 4;
    int*   rs     = (int*)p;   p += (size_t)N * 4;
    int*   deg    = (int*)p;   p += (size_t)N * 4;
    int*   binBase= (int*)p;   p += (NBINMAX + 2) * 4;
    // zeroed region: binCnt | binCur
    int*   binCnt = (int*)p;   p += NBINMAX * 4;
    int*   binCur = (int*)p;   p += NBINMAX * 4;

    hipMemsetAsync(binCnt, 0, 2 * NBINMAX * 4, stream);

    k_count<<<ceil_div(E, CHUNK), 256, 0, stream>>>(ei + E, binCnt, E, nbins);
    k_binoff<<<1, 256, 0, stream>>>(binCnt, binBase, nbins, E);
    k_bin<<<ceil_div(E, CHUNK), 256, 0, stream>>>(ei, ei + E, binBase, binCur, binned, E, nbins);
    k_fillc2<<<nbins, 256, 0, stream>>>(binned, binBase, col, rs, deg, dinv, N);

    k_gemm<128, false><<<ceil_div(N, 64), 256, 0, stream>>>(x, W1, A, dinv, N);
    k_agg<<<ceil_div(N * 8, 256), 256, 0, stream>>>(A, Bb, rs, deg, col, dinv, b1, N, 1);
    k_gemm<64, true><<<ceil_div(N, 64), 256, 0, stream>>>(Bb, W2, A, dinv, N);
    k_agg<<<ceil_div(N * 8, 256), 256, 0, stream>>>(A, Bb, rs, deg, col, dinv, b2, N, 1);
    k_gemm<64, true><<<ceil_div(N, 64), 256, 0, stream>>>(Bb, W3, A, dinv, N);
    k_agg<<<ceil_div(N * 8, 256), 256, 0, stream>>>(A, Bb, rs, deg, col, dinv, b3, N, 0);

    k_pool_head<<<1024, 256, 0, stream>>>(Bb, bat, cent, rb, out, N);
}

// Round 2
// 331.540 us; speedup vs baseline: 1.0699x; 1.0415x over previous
//
#include <hip/hip_runtime.h>

#define HID 64
#define NCLS 16
#define NCENT 3
#define NCENTS (NCLS * NCENT)
#define BSHIFT 9               // 512 nodes per bin
#define BINW (1 << BSHIFT)
#define NBINMAX 256            // supports N <= 131072
#define CHUNK 4096             // edges per k_bin/k_count block
#define EPT (CHUNK / 256)
#define NU 8                   // k_agg gather pipeline depth

static inline int ceil_div(int a, int b) { return (a + b - 1) / b; }

__device__ inline unsigned short f2bf(float f) {   // round-to-nearest-even
    unsigned int u = __float_as_uint(f);
    return (unsigned short)((u + 0x7FFFu + ((u >> 16) & 1u)) >> 16);
}
__device__ inline unsigned int pack2bf(float lo, float hi) {
    return (unsigned int)f2bf(lo) | ((unsigned int)f2bf(hi) << 16);
}
__device__ inline float bf2f(unsigned short h) {
    return __uint_as_float(((unsigned int)h) << 16);
}
__device__ inline float bflo(unsigned int u) { return __uint_as_float(u << 16); }
__device__ inline float bfhi(unsigned int u) { return __uint_as_float(u & 0xFFFF0000u); }

typedef short bf16x8 __attribute__((ext_vector_type(8)));
typedef float f32x4 __attribute__((ext_vector_type(4)));

// ---- edge binning (counting-sort by dst>>BSHIFT) ------------------------

__global__ void k_count(const int* __restrict__ dst, int* __restrict__ binCnt,
                        int E, int nbins) {
    __shared__ int c[NBINMAX];
    for (int i = threadIdx.x; i < nbins; i += 256) c[i] = 0;
    __syncthreads();
    int e = blockIdx.x * CHUNK + threadIdx.x;
#pragma unroll
    for (int j = 0; j < EPT; j++, e += 256)
        if (e < E) atomicAdd(&c[dst[e] >> BSHIFT], 1);
    __syncthreads();
    for (int i = threadIdx.x; i < nbins; i += 256)
        if (c[i] > 0) atomicAdd(&binCnt[i], c[i]);
}

__global__ void k_binoff(const int* __restrict__ binCnt, int* __restrict__ binBase,
                         int nbins, int E) {
    __shared__ int ts[NBINMAX];
    int t = threadIdx.x;
    int v = (t < nbins) ? binCnt[t] : 0;
    ts[t] = v;
    __syncthreads();
    for (int off = 1; off < NBINMAX; off <<= 1) {
        int x = (t >= off) ? ts[t - off] : 0;
        __syncthreads();
        ts[t] += x;
        __syncthreads();
    }
    if (t < nbins) binBase[t] = ts[t] - v;   // exclusive
    if (t == 0) binBase[nbins] = E;
}

// Stage CHUNK edges in LDS packed by bin; copy out contiguous per-bin segments.
__global__ __launch_bounds__(256) void k_bin(const int* __restrict__ src,
                                             const int* __restrict__ dst,
                                             const int* __restrict__ binBase,
                                             int* __restrict__ binCur,
                                             int2* __restrict__ binned,
                                             int E, int nbins) {
    __shared__ int cnt[NBINMAX], off[NBINMAX], gbase[NBINMAX];
    __shared__ int2 stage[CHUNK];
    const int c0 = blockIdx.x * CHUNK;
    const int tid = threadIdx.x;
    cnt[tid] = 0;
    __syncthreads();
    int sv[EPT], dv[EPT];
#pragma unroll
    for (int j = 0; j < EPT; j++) {
        int e = c0 + j * 256 + tid;
        dv[j] = -1;
        if (e < E) {
            sv[j] = src[e];
            dv[j] = dst[e];
            atomicAdd(&cnt[dv[j] >> BSHIFT], 1);
        }
    }
    __syncthreads();
    off[tid] = cnt[tid];
    __syncthreads();
    for (int o = 1; o < NBINMAX; o <<= 1) {
        int x = (tid >= o) ? off[tid - o] : 0;
        __syncthreads();
        off[tid] += x;
        __syncthreads();
    }
    int excl = off[tid] - cnt[tid];
    __syncthreads();
    off[tid] = excl;
    gbase[tid] = (tid < nbins && cnt[tid] > 0) ? atomicAdd(&binCur[tid], cnt[tid]) : 0;
    cnt[tid] = 0;  // reuse as local cursor
    __syncthreads();
#pragma unroll
    for (int j = 0; j < EPT; j++)
        if (dv[j] >= 0) {
            int b = dv[j] >> BSHIFT;
            int pos = off[b] + atomicAdd(&cnt[b], 1);
            stage[pos] = make_int2(sv[j], dv[j]);
        }
    __syncthreads();
    int tot = min(CHUNK, E - c0);
    for (int i = tid; i < tot; i += 256) {
        int2 v = stage[i];
        int b = v.y >> BSHIFT;
        binned[binBase[b] + gbase[b] + (i - off[b])] = v;
    }
}

// One block per bin: fused hist + local scan + deg/rs/dinv write + col scatter.
__global__ __launch_bounds__(256) void k_fillc2(const int2* __restrict__ binned,
                                                const int* __restrict__ binBase,
                                                int* __restrict__ col,
                                                int* __restrict__ rs_out,
                                                int* __restrict__ deg_out,
                                                float* __restrict__ dinv_out, int N) {
    __shared__ int c[BINW];      // histogram, then cursor
    __shared__ int rsl[BINW];    // per-node row start
    __shared__ int ts[256];
    int b = blockIdx.x;
    int s = binBase[b], e = binBase[b + 1];
    int n0 = b << BSHIFT;
    int t = threadIdx.x;
    c[2 * t] = 0; c[2 * t + 1] = 0;
    __syncthreads();
    for (int i = s + t; i < e; i += 256)
        atomicAdd(&c[binned[i].y - n0], 1);
    __syncthreads();
    int v0 = c[2 * t], v1 = c[2 * t + 1];
    ts[t] = v0 + v1;
    __syncthreads();
    for (int off = 1; off < 256; off <<= 1) {
        int x = (t >= off) ? ts[t - off] : 0;
        __syncthreads();
        ts[t] += x;
        __syncthreads();
    }
    int base = binBase[b] + ts[t] - (v0 + v1);  // exclusive over node pairs
    rsl[2 * t] = base;
    rsl[2 * t + 1] = base + v0;
    int n = n0 + 2 * t;
    if (n < N) {
        deg_out[n] = v0; rs_out[n] = base;
        dinv_out[n] = rsqrtf((float)(v0 + 1));   // +1 self loop
    }
    if (n + 1 < N) {
        deg_out[n + 1] = v1; rs_out[n + 1] = base + v0;
        dinv_out[n + 1] = rsqrtf((float)(v1 + 1));
    }
    c[2 * t] = 0; c[2 * t + 1] = 0;   // reset as cursor
    __syncthreads();
    for (int i = s + t; i < e; i += 256) {
        int2 v = binned[i];
        int lo = v.y - n0;
        int pos = rsl[lo] + atomicAdd(&c[lo], 1);
        col[pos] = v.x;
    }
}

// ---- W repack: split fp32 W into bf16 hi + bf16 residual, MFMA lane layout
// layout: frag[(kt*4+ct)*64 + lane][j] = W[kt*32 + (lane>>4)*8 + j][ct*16 + (lane&15)]

__device__ void wprep_one(const float* __restrict__ W, unsigned short* __restrict__ Wh,
                          unsigned short* __restrict__ Wl, int K) {
    for (int idx = threadIdx.x; idx < K * 64; idx += 256) {
        int k = idx >> 6, colc = idx & 63;
        float f = W[idx];
        unsigned short h = f2bf(f);
        unsigned short lo = f2bf(f - bf2f(h));
        int kt = k >> 5, kin = k & 31, ct = colc >> 4;
        int ln = ((kin >> 3) << 4) | (colc & 15);
        int o = (((kt * 4 + ct) * 64) + ln) * 8 + (kin & 7);
        Wh[o] = h; Wl[o] = lo;
    }
}

__global__ void k_wprep(const float* __restrict__ W1, const float* __restrict__ W2,
                        const float* __restrict__ W3,
                        unsigned short* __restrict__ W1h, unsigned short* __restrict__ W1l,
                        unsigned short* __restrict__ W2h, unsigned short* __restrict__ W2l,
                        unsigned short* __restrict__ W3h, unsigned short* __restrict__ W3l) {
    if (blockIdx.x == 0) wprep_one(W1, W1h, W1l, 128);
    else if (blockIdx.x == 1) wprep_one(W2, W2h, W2l, 64);
    else wprep_one(W3, W3h, W3l, 64);
}

// ---- MFMA GEMM: out[N,64] = dinv[row] * (A[N,K] @ W[K,64]), bf16 out ----
// BF=false: fp32 input split into bf16 hi+lo (3-term product, fp32-grade).
// BF=true : bf16 input, W split hi+lo (2-term product).
// 4 waves/block, wave = 16 rows x 64 cols, mfma_f32_16x16x32_bf16.
// A frag: lane l -> row=(l&15), k = 8*(l>>4)+j (contiguous 16B load).
// C/D  : col = lane&15, row = (lane>>4)*4 + reg (m89-verified mapping).

template <int K, bool BF>
__global__ __launch_bounds__(256) void k_gemm_mfma(const void* __restrict__ Ain,
                                                   const unsigned short* __restrict__ Wh,
                                                   const unsigned short* __restrict__ Wl,
                                                   unsigned short* __restrict__ out,
                                                   const float* __restrict__ dinv, int N) {
    const int lane = threadIdx.x & 63;
    const int wave = threadIdx.x >> 6;
    const int row0 = blockIdx.x * 64 + wave * 16;
    int arow = row0 + (lane & 15);
    if (arow > N - 1) arow = N - 1;          // clamp; stores are guarded
    const int kb = (lane >> 4) * 8;

    f32x4 acc[4] = {};

#pragma unroll
    for (int kt = 0; kt < K / 32; ++kt) {
        bf16x8 ah, al;
        if (BF) {
            ah = *(const bf16x8*)((const unsigned short*)Ain + (size_t)arow * K + kt * 32 + kb);
        } else {
            const float* ap = (const float*)Ain + (size_t)arow * K + kt * 32 + kb;
            float4 f0 = *(const float4*)ap;
            float4 f1 = *(const float4*)(ap + 4);
            float fv[8] = {f0.x, f0.y, f0.z, f0.w, f1.x, f1.y, f1.z, f1.w};
#pragma unroll
            for (int j = 0; j < 8; ++j) {
                unsigned short h = f2bf(fv[j]);
                ah[j] = (short)h;
                al[j] = (short)f2bf(fv[j] - bf2f(h));
            }
        }
#pragma unroll
        for (int ct = 0; ct < 4; ++ct) {
            const size_t wo = ((size_t)(kt * 4 + ct) * 64 + lane) * 8;
            bf16x8 wh = *(const bf16x8*)(Wh + wo);
            bf16x8 wl = *(const bf16x8*)(Wl + wo);
            acc[ct] = __builtin_amdgcn_mfma_f32_16x16x32_bf16(ah, wh, acc[ct], 0, 0, 0);
            if (!BF)
                acc[ct] = __builtin_amdgcn_mfma_f32_16x16x32_bf16(al, wh, acc[ct], 0, 0, 0);
            acc[ct] = __builtin_amdgcn_mfma_f32_16x16x32_bf16(ah, wl, acc[ct], 0, 0, 0);
        }
    }

    const int rb = row0 + (lane >> 4) * 4;
    const int cb = lane & 15;
#pragma unroll
    for (int i = 0; i < 4; ++i) {
        int row = rb + i;
        if (row < N) {
            float d = dinv[row];
#pragma unroll
            for (int ct = 0; ct < 4; ++ct)
                out[(size_t)row * HID + ct * 16 + cb] = f2bf(d * acc[ct][i]);
        }
    }
}

// ---- aggregation: 8-lane group per node, lane = 8 feats (uint4 = 16B) ----
// Table rows are pre-scaled by dinv[src] in the GEMM epilogue: pure sum of
// gathered rows; clamped tail repeats col[last], corrected once after loop.

__global__ void k_agg(const unsigned short* __restrict__ tin,
                      unsigned short* __restrict__ out,
                      const int* __restrict__ rs, const int* __restrict__ deg,
                      const int* __restrict__ col,
                      const float* __restrict__ dinv, const float* __restrict__ bias,
                      int N, int relu) {
    int node = (blockIdx.x * blockDim.x + threadIdx.x) >> 3;
    int l = threadIdx.x & 7;
    if (node >= N) return;
    float di = dinv[node];
    uint4 tb = ((const uint4*)(tin + (size_t)node * HID))[l];
    float a0 = bflo(tb.x), a1 = bfhi(tb.x);
    float a2 = bflo(tb.y), a3 = bfhi(tb.y);
    float a4 = bflo(tb.z), a5 = bfhi(tb.z);
    float a6 = bflo(tb.w), a7 = bfhi(tb.w);

    int beg = rs[node];
    int cnt = deg[node];
    int last = beg + cnt - 1;
    for (int e = 0; e < cnt; e += NU) {
        int sv[NU];
#pragma unroll
        for (int j = 0; j < NU; j++) {
            int idx = beg + e + j;
            sv[j] = col[idx < last ? idx : last];
        }
        uint4 vv[NU];
#pragma unroll
        for (int j = 0; j < NU; j++) vv[j] = ((const uint4*)(tin + (size_t)sv[j] * HID))[l];
#pragma unroll
        for (int j = 0; j < NU; j++) {
            a0 += bflo(vv[j].x); a1 += bfhi(vv[j].x);
            a2 += bflo(vv[j].y); a3 += bfhi(vv[j].y);
            a4 += bflo(vv[j].z); a5 += bfhi(vv[j].z);
            a6 += bflo(vv[j].w); a7 += bfhi(vv[j].w);
        }
    }
    int pad = (NU - (cnt & (NU - 1))) & (NU - 1);
    if (cnt > 0 && pad > 0) {
        float fp = (float)pad;
        uint4 vl = ((const uint4*)(tin + (size_t)col[last] * HID))[l];  // L1 hit
        a0 = fmaf(-fp, bflo(vl.x), a0); a1 = fmaf(-fp, bfhi(vl.x), a1);
        a2 = fmaf(-fp, bflo(vl.y), a2); a3 = fmaf(-fp, bfhi(vl.y), a3);
        a4 = fmaf(-fp, bflo(vl.z), a4); a5 = fmaf(-fp, bfhi(vl.z), a5);
        a6 = fmaf(-fp, bflo(vl.w), a6); a7 = fmaf(-fp, bfhi(vl.w), a7);
    }
    float4 b0 = ((const float4*)bias)[2 * l];
    float4 b1 = ((const float4*)bias)[2 * l + 1];
    a0 = fmaf(di, a0, b0.x); a1 = fmaf(di, a1, b0.y);
    a2 = fmaf(di, a2, b0.z); a3 = fmaf(di, a3, b0.w);
    a4 = fmaf(di, a4, b1.x); a5 = fmaf(di, a5, b1.y);
    a6 = fmaf(di, a6, b1.z); a7 = fmaf(di, a7, b1.w);
    if (relu) {
        a0 = fmaxf(a0, 0.f); a1 = fmaxf(a1, 0.f); a2 = fmaxf(a2, 0.f); a3 = fmaxf(a3, 0.f);
        a4 = fmaxf(a4, 0.f); a5 = fmaxf(a5, 0.f); a6 = fmaxf(a6, 0.f); a7 = fmaxf(a7, 0.f);
    }
    uint4 o;
    o.x = pack2bf(a0, a1); o.y = pack2bf(a2, a3);
    o.z = pack2bf(a4, a5); o.w = pack2bf(a6, a7);
    ((uint4*)(out + (size_t)node * HID))[l] = o;
}

// ---- fused mean-pool + centroid-distance head (bf16 input) --------------

__global__ void k_pool_head(const unsigned short* __restrict__ h,
                            const int* __restrict__ batch,
                            const float* __restrict__ cent, const float* __restrict__ rbias,
                            float* __restrict__ out, int N) {
    int g = blockIdx.x;
    int lo = 0, hi = N;
    while (lo < hi) { int mid = (lo + hi) >> 1; if (batch[mid] < g) lo = mid + 1; else hi = mid; }
    int s = lo;
    lo = 0; hi = N;
    while (lo < hi) { int mid = (lo + hi) >> 1; if (batch[mid] < g + 1) lo = mid + 1; else hi = mid; }
    int e = lo;

    __shared__ float part[4][HID];
    __shared__ float embS[HID];
    __shared__ float dS[NCENTS];
    __shared__ float dpcS[NCLS];

    int lane = threadIdx.x & 63, wid = threadIdx.x >> 6;
    float acc = 0.0f;
    for (int i = s + wid; i < e; i += 4) acc += bf2f(h[(size_t)i * HID + lane]);
    part[wid][lane] = acc;
    __syncthreads();
    if (wid == 0) {
        float v = part[0][lane] + part[1][lane] + part[2][lane] + part[3][lane];
        embS[lane] = v / fmaxf((float)(e - s), 1.0f);
    }
    __syncthreads();
    if (threadIdx.x < NCENTS) {
        const float* c = cent + threadIdx.x * HID;
        float d = 0.0f;
        for (int k = 0; k < HID; k++) { float df = embS[k] - c[k]; d = fmaf(df, df, d); }
        dS[threadIdx.x] = d;
    }
    __syncthreads();
    if (threadIdx.x < NCLS) {
        float m = fminf(dS[threadIdx.x * 3],
                        fminf(dS[threadIdx.x * 3 + 1], dS[threadIdx.x * 3 + 2]));
        dpcS[threadIdx.x] = m;
        out[g * (NCLS + 1) + threadIdx.x] = -m;
    }
    __syncthreads();
    if (threadIdx.x == 0) {
        float m = dpcS[0];
        for (int i = 1; i < NCLS; i++) m = fminf(m, dpcS[i]);
        out[g * (NCLS + 1) + NCLS] = m - rbias[0];
    }
}

// ---- launch -------------------------------------------------------------

extern "C" void kernel_launch(void* const* d_in, const int* in_sizes, int n_in,
                              void* d_out, int out_size, void* d_ws, size_t ws_size,
                              hipStream_t stream) {
    const float* x    = (const float*)d_in[0];
    const int*   ei   = (const int*)d_in[1];   // [2, E]: row0 = src, row1 = dst
    const int*   bat  = (const int*)d_in[2];
    const float* W1   = (const float*)d_in[3];
    const float* b1   = (const float*)d_in[4];
    const float* W2   = (const float*)d_in[5];
    const float* b2   = (const float*)d_in[6];
    const float* W3   = (const float*)d_in[7];
    const float* b3   = (const float*)d_in[8];
    const float* cent = (const float*)d_in[9];
    const float* rb   = (const float*)d_in[10];
    float* out = (float*)d_out;

    const int N = in_sizes[0] / 128;
    const int E = in_sizes[1] / 2;
    const int nbins = (N + BINW - 1) >> BSHIFT;

    char* p = (char*)d_ws;
    unsigned short* A  = (unsigned short*)p; p += (size_t)N * HID * 2;  // bf16 gather table (dinv-prescaled)
    unsigned short* Bb = (unsigned short*)p; p += (size_t)N * HID * 2;  // bf16 agg output
    int2*  binned = (int2*)p;  p += (size_t)E * 8;
    int*   col    = (int*)p;   p += (size_t)E * 4;
    float* dinv   = (float*)p; p += (size_t)N * 4;
    int*   rs     = (int*)p;   p += (size_t)N * 4;
    int*   deg    = (int*)p;   p += (size_t)N * 4;
    int*   binBase= (int*)p;   p += (NBINMAX + 2) * 4;
    // zeroed region: binCnt | binCur
    int*   binCnt = (int*)p;   p += NBINMAX * 4;
    int*   binCur = (int*)p;   p += NBINMAX * 4;
    p = (char*)(((uintptr_t)p + 15) & ~(uintptr_t)15);
    unsigned short* W1h = (unsigned short*)p; p += 8192 * 2;
    unsigned short* W1l = (unsigned short*)p; p += 8192 * 2;
    unsigned short* W2h = (unsigned short*)p; p += 4096 * 2;
    unsigned short* W2l = (unsigned short*)p; p += 4096 * 2;
    unsigned short* W3h = (unsigned short*)p; p += 4096 * 2;
    unsigned short* W3l = (unsigned short*)p; p += 4096 * 2;

    hipMemsetAsync(binCnt, 0, 2 * NBINMAX * 4, stream);

    k_wprep<<<3, 256, 0, stream>>>(W1, W2, W3, W1h, W1l, W2h, W2l, W3h, W3l);

    k_count<<<ceil_div(E, CHUNK), 256, 0, stream>>>(ei + E, binCnt, E, nbins);
    k_binoff<<<1, 256, 0, stream>>>(binCnt, binBase, nbins, E);
    k_bin<<<ceil_div(E, CHUNK), 256, 0, stream>>>(ei, ei + E, binBase, binCur, binned, E, nbins);
    k_fillc2<<<nbins, 256, 0, stream>>>(binned, binBase, col, rs, deg, dinv, N);

    k_gemm_mfma<128, false><<<ceil_div(N, 64), 256, 0, stream>>>(x, W1h, W1l, A, dinv, N);
    k_agg<<<ceil_div(N * 8, 256), 256, 0, stream>>>(A, Bb, rs, deg, col, dinv, b1, N, 1);
    k_gemm_mfma<64, true><<<ceil_div(N, 64), 256, 0, stream>>>(Bb, W2h, W2l, A, dinv, N);
    k_agg<<<ceil_div(N * 8, 256), 256, 0, stream>>>(A, Bb, rs, deg, col, dinv, b2, N, 1);
    k_gemm_mfma<64, true><<<ceil_div(N, 64), 256, 0, stream>>>(Bb, W3h, W3l, A, dinv, N);
    k_agg<<<ceil_div(N * 8, 256), 256, 0, stream>>>(A, Bb, rs, deg, col, dinv, b3, N, 0);

    k_pool_head<<<1024, 256, 0, stream>>>(Bb, bat, cent, rb, out, N);
}

// Round 3
// 306.110 us; speedup vs baseline: 1.1588x; 1.0831x over previous
//
#include <hip/hip_runtime.h>

#define HID 64
#define NCLS 16
#define NCENT 3
#define NCENTS (NCLS * NCENT)
#define BSHIFT 9               // 512 nodes per bin
#define BINW (1 << BSHIFT)
#define NBINMAX 256            // supports N <= 131072
#define CHUNK 4096             // edges per k_bin/k_count block
#define EPT (CHUNK / 256)
#define NU 8                   // k_agg gather pipeline depth

static inline int ceil_div(int a, int b) { return (a + b - 1) / b; }

__device__ inline unsigned short f2bf(float f) {   // round-to-nearest-even
    unsigned int u = __float_as_uint(f);
    return (unsigned short)((u + 0x7FFFu + ((u >> 16) & 1u)) >> 16);
}
__device__ inline unsigned int pack2bf(float lo, float hi) {
    return (unsigned int)f2bf(lo) | ((unsigned int)f2bf(hi) << 16);
}
__device__ inline float bf2f(unsigned short h) {
    return __uint_as_float(((unsigned int)h) << 16);
}
__device__ inline float bflo(unsigned int u) { return __uint_as_float(u << 16); }
__device__ inline float bfhi(unsigned int u) { return __uint_as_float(u & 0xFFFF0000u); }

typedef short bf16x8 __attribute__((ext_vector_type(8)));
typedef float f32x4 __attribute__((ext_vector_type(4)));

// ---- W repack: split fp32 W into bf16 hi + bf16 residual, MFMA lane layout
// layout: frag[(kt*4+ct)*64 + lane][j] = W[kt*32 + (lane>>4)*8 + j][ct*16 + (lane&15)]

__device__ void wprep_one(const float* __restrict__ W, unsigned short* __restrict__ Wh,
                          unsigned short* __restrict__ Wl, int K) {
    for (int idx = threadIdx.x; idx < K * 64; idx += 256) {
        int k = idx >> 6, colc = idx & 63;
        float f = W[idx];
        unsigned short h = f2bf(f);
        unsigned short lo = f2bf(f - bf2f(h));
        int kt = k >> 5, kin = k & 31, ct = colc >> 4;
        int ln = ((kin >> 3) << 4) | (colc & 15);
        int o = (((kt * 4 + ct) * 64) + ln) * 8 + (kin & 7);
        Wh[o] = h; Wl[o] = lo;
    }
}

// ---- edge binning (counting-sort by dst>>BSHIFT); last 3 blocks do wprep --

__global__ void k_count_w(const int* __restrict__ dst, int* __restrict__ binCnt,
                          int E, int nbins,
                          const float* __restrict__ W1, const float* __restrict__ W2,
                          const float* __restrict__ W3,
                          unsigned short* __restrict__ W1h, unsigned short* __restrict__ W1l,
                          unsigned short* __restrict__ W2h, unsigned short* __restrict__ W2l,
                          unsigned short* __restrict__ W3h, unsigned short* __restrict__ W3l) {
    if (blockIdx.x >= gridDim.x - 3) {
        int w = blockIdx.x - (gridDim.x - 3);
        if (w == 0) wprep_one(W1, W1h, W1l, 128);
        else if (w == 1) wprep_one(W2, W2h, W2l, 64);
        else wprep_one(W3, W3h, W3l, 64);
        return;
    }
    __shared__ int c[NBINMAX];
    for (int i = threadIdx.x; i < nbins; i += 256) c[i] = 0;
    __syncthreads();
    int e = blockIdx.x * CHUNK + threadIdx.x;
#pragma unroll
    for (int j = 0; j < EPT; j++, e += 256)
        if (e < E) atomicAdd(&c[dst[e] >> BSHIFT], 1);
    __syncthreads();
    for (int i = threadIdx.x; i < nbins; i += 256)
        if (c[i] > 0) atomicAdd(&binCnt[i], c[i]);
}

__global__ void k_binoff(const int* __restrict__ binCnt, int* __restrict__ binBase,
                         int nbins, int E) {
    __shared__ int ts[NBINMAX];
    int t = threadIdx.x;
    int v = (t < nbins) ? binCnt[t] : 0;
    ts[t] = v;
    __syncthreads();
    for (int off = 1; off < NBINMAX; off <<= 1) {
        int x = (t >= off) ? ts[t - off] : 0;
        __syncthreads();
        ts[t] += x;
        __syncthreads();
    }
    if (t < nbins) binBase[t] = ts[t] - v;   // exclusive
    if (t == 0) binBase[nbins] = E;
}

// Stage CHUNK edges in LDS packed by bin; copy out contiguous per-bin segments.
__global__ __launch_bounds__(256) void k_bin(const int* __restrict__ src,
                                             const int* __restrict__ dst,
                                             const int* __restrict__ binBase,
                                             int* __restrict__ binCur,
                                             int2* __restrict__ binned,
                                             int E, int nbins) {
    __shared__ int cnt[NBINMAX], off[NBINMAX], gbase[NBINMAX];
    __shared__ int2 stage[CHUNK];
    const int c0 = blockIdx.x * CHUNK;
    const int tid = threadIdx.x;
    cnt[tid] = 0;
    __syncthreads();
    int sv[EPT], dv[EPT];
#pragma unroll
    for (int j = 0; j < EPT; j++) {
        int e = c0 + j * 256 + tid;
        dv[j] = -1;
        if (e < E) {
            sv[j] = src[e];
            dv[j] = dst[e];
            atomicAdd(&cnt[dv[j] >> BSHIFT], 1);
        }
    }
    __syncthreads();
    off[tid] = cnt[tid];
    __syncthreads();
    for (int o = 1; o < NBINMAX; o <<= 1) {
        int x = (tid >= o) ? off[tid - o] : 0;
        __syncthreads();
        off[tid] += x;
        __syncthreads();
    }
    int excl = off[tid] - cnt[tid];
    __syncthreads();
    off[tid] = excl;
    gbase[tid] = (tid < nbins && cnt[tid] > 0) ? atomicAdd(&binCur[tid], cnt[tid]) : 0;
    cnt[tid] = 0;  // reuse as local cursor
    __syncthreads();
#pragma unroll
    for (int j = 0; j < EPT; j++)
        if (dv[j] >= 0) {
            int b = dv[j] >> BSHIFT;
            int pos = off[b] + atomicAdd(&cnt[b], 1);
            stage[pos] = make_int2(sv[j], dv[j]);
        }
    __syncthreads();
    int tot = min(CHUNK, E - c0);
    for (int i = tid; i < tot; i += 256) {
        int2 v = stage[i];
        int b = v.y >> BSHIFT;
        binned[binBase[b] + gbase[b] + (i - off[b])] = v;
    }
}

// One block per bin: fused hist + local scan + deg/rs/dinv write + col scatter.
__global__ __launch_bounds__(256) void k_fillc2(const int2* __restrict__ binned,
                                                const int* __restrict__ binBase,
                                                int* __restrict__ col,
                                                int* __restrict__ rs_out,
                                                int* __restrict__ deg_out,
                                                float* __restrict__ dinv_out, int N) {
    __shared__ int c[BINW];      // histogram, then cursor
    __shared__ int rsl[BINW];    // per-node row start
    __shared__ int ts[256];
    int b = blockIdx.x;
    int s = binBase[b], e = binBase[b + 1];
    int n0 = b << BSHIFT;
    int t = threadIdx.x;
    c[2 * t] = 0; c[2 * t + 1] = 0;
    __syncthreads();
    for (int i = s + t; i < e; i += 256)
        atomicAdd(&c[binned[i].y - n0], 1);
    __syncthreads();
    int v0 = c[2 * t], v1 = c[2 * t + 1];
    ts[t] = v0 + v1;
    __syncthreads();
    for (int off = 1; off < 256; off <<= 1) {
        int x = (t >= off) ? ts[t - off] : 0;
        __syncthreads();
        ts[t] += x;
        __syncthreads();
    }
    int base = binBase[b] + ts[t] - (v0 + v1);  // exclusive over node pairs
    rsl[2 * t] = base;
    rsl[2 * t + 1] = base + v0;
    int n = n0 + 2 * t;
    if (n < N) {
        deg_out[n] = v0; rs_out[n] = base;
        dinv_out[n] = rsqrtf((float)(v0 + 1));   // +1 self loop
    }
    if (n + 1 < N) {
        deg_out[n + 1] = v1; rs_out[n + 1] = base + v0;
        dinv_out[n + 1] = rsqrtf((float)(v1 + 1));
    }
    c[2 * t] = 0; c[2 * t + 1] = 0;   // reset as cursor
    __syncthreads();
    for (int i = s + t; i < e; i += 256) {
        int2 v = binned[i];
        int lo = v.y - n0;
        int pos = rsl[lo] + atomicAdd(&c[lo], 1);
        col[pos] = v.x;
    }
}

// ---- MFMA GEMM (layer 1 only): out = dinv[row]*(x[N,128] @ W1), bf16 out --

template <int K>
__global__ __launch_bounds__(256) void k_gemm_mfma(const float* __restrict__ Ain,
                                                   const unsigned short* __restrict__ Wh,
                                                   const unsigned short* __restrict__ Wl,
                                                   unsigned short* __restrict__ out,
                                                   const float* __restrict__ dinv, int N) {
    const int lane = threadIdx.x & 63;
    const int wave = threadIdx.x >> 6;
    const int row0 = blockIdx.x * 64 + wave * 16;
    int arow = row0 + (lane & 15);
    if (arow > N - 1) arow = N - 1;          // clamp; stores are guarded
    const int kb = (lane >> 4) * 8;

    f32x4 acc[4] = {};

#pragma unroll
    for (int kt = 0; kt < K / 32; ++kt) {
        bf16x8 ah, al;
        const float* ap = Ain + (size_t)arow * K + kt * 32 + kb;
        float4 f0 = *(const float4*)ap;
        float4 f1 = *(const float4*)(ap + 4);
        float fv[8] = {f0.x, f0.y, f0.z, f0.w, f1.x, f1.y, f1.z, f1.w};
#pragma unroll
        for (int j = 0; j < 8; ++j) {
            unsigned short h = f2bf(fv[j]);
            ah[j] = (short)h;
            al[j] = (short)f2bf(fv[j] - bf2f(h));
        }
#pragma unroll
        for (int ct = 0; ct < 4; ++ct) {
            const size_t wo = ((size_t)(kt * 4 + ct) * 64 + lane) * 8;
            bf16x8 wh = *(const bf16x8*)(Wh + wo);
            bf16x8 wl = *(const bf16x8*)(Wl + wo);
            acc[ct] = __builtin_amdgcn_mfma_f32_16x16x32_bf16(ah, wh, acc[ct], 0, 0, 0);
            acc[ct] = __builtin_amdgcn_mfma_f32_16x16x32_bf16(al, wh, acc[ct], 0, 0, 0);
            acc[ct] = __builtin_amdgcn_mfma_f32_16x16x32_bf16(ah, wl, acc[ct], 0, 0, 0);
        }
    }

    const int rb = row0 + (lane >> 4) * 4;
    const int cb = lane & 15;
#pragma unroll
    for (int i = 0; i < 4; ++i) {
        int row = rb + i;
        if (row < N) {
            float d = dinv[row];
#pragma unroll
            for (int ct = 0; ct < 4; ++ct)
                out[(size_t)row * HID + ct * 16 + cb] = f2bf(d * acc[ct][i]);
        }
    }
}

// ---- fused aggregation + next-layer GEMM --------------------------------
// Gather phase (8 lanes/node, NU pipeline, col via shfl broadcast), then
// t = relu(di*acc + bias) staged bf16 in LDS (32 nodes x 64 feats), then
// per-wave MFMA t @ W (Wh+Wl split) -> write dinv-prescaled bf16 table.

__global__ __launch_bounds__(256) void k_aggf(const unsigned short* __restrict__ tin,
                                              unsigned short* __restrict__ tout,
                                              const int* __restrict__ rs,
                                              const int* __restrict__ deg,
                                              const int* __restrict__ col,
                                              const float* __restrict__ dinv,
                                              const float* __restrict__ bias,
                                              const unsigned short* __restrict__ Wh,
                                              const unsigned short* __restrict__ Wl,
                                              int N) {
    __shared__ unsigned int tl[32][36];   // 32 nodes x 64 bf16, rows padded to 144B
    const int tid = threadIdx.x;
    const int lane = tid & 63;
    const int wave = tid >> 6;
    const int group = tid >> 3;           // 0..31
    const int l = tid & 7;
    int node = blockIdx.x * 32 + group;
    int cnode = node < N ? node : N - 1;  // inactive groups duplicate last node

    float di = dinv[cnode];
    uint4 tb = ((const uint4*)(tin + (size_t)cnode * HID))[l];
    float a0 = bflo(tb.x), a1 = bfhi(tb.x);
    float a2 = bflo(tb.y), a3 = bfhi(tb.y);
    float a4 = bflo(tb.z), a5 = bfhi(tb.z);
    float a6 = bflo(tb.w), a7 = bfhi(tb.w);

    int beg = rs[cnode];
    int cnt = deg[cnode];
    int last = beg + cnt - 1;
    const int gbase = lane & 56;          // group base within wave
    for (int e = 0; e < cnt; e += NU) {
        int idx = beg + e + l;
        int cv = col[idx < last ? idx : last];
        int sv[NU];
#pragma unroll
        for (int j = 0; j < NU; j++) sv[j] = __shfl(cv, gbase + j, 64);
        uint4 vv[NU];
#pragma unroll
        for (int j = 0; j < NU; j++) vv[j] = ((const uint4*)(tin + (size_t)sv[j] * HID))[l];
#pragma unroll
        for (int j = 0; j < NU; j++) {
            a0 += bflo(vv[j].x); a1 += bfhi(vv[j].x);
            a2 += bflo(vv[j].y); a3 += bfhi(vv[j].y);
            a4 += bflo(vv[j].z); a5 += bfhi(vv[j].z);
            a6 += bflo(vv[j].w); a7 += bfhi(vv[j].w);
        }
    }
    int pad = (NU - (cnt & (NU - 1))) & (NU - 1);
    if (cnt > 0 && pad > 0) {
        float fp = (float)pad;
        uint4 vl = ((const uint4*)(tin + (size_t)col[last] * HID))[l];  // L1 hit
        a0 = fmaf(-fp, bflo(vl.x), a0); a1 = fmaf(-fp, bfhi(vl.x), a1);
        a2 = fmaf(-fp, bflo(vl.y), a2); a3 = fmaf(-fp, bfhi(vl.y), a3);
        a4 = fmaf(-fp, bflo(vl.z), a4); a5 = fmaf(-fp, bfhi(vl.z), a5);
        a6 = fmaf(-fp, bflo(vl.w), a6); a7 = fmaf(-fp, bfhi(vl.w), a7);
    }
    float4 b0 = ((const float4*)bias)[2 * l];
    float4 b1 = ((const float4*)bias)[2 * l + 1];
    a0 = fmaxf(fmaf(di, a0, b0.x), 0.f); a1 = fmaxf(fmaf(di, a1, b0.y), 0.f);
    a2 = fmaxf(fmaf(di, a2, b0.z), 0.f); a3 = fmaxf(fmaf(di, a3, b0.w), 0.f);
    a4 = fmaxf(fmaf(di, a4, b1.x), 0.f); a5 = fmaxf(fmaf(di, a5, b1.y), 0.f);
    a6 = fmaxf(fmaf(di, a6, b1.z), 0.f); a7 = fmaxf(fmaf(di, a7, b1.w), 0.f);

    uint4 o;
    o.x = pack2bf(a0, a1); o.y = pack2bf(a2, a3);
    o.z = pack2bf(a4, a5); o.w = pack2bf(a6, a7);
    *(uint4*)&tl[group][4 * l] = o;
    __syncthreads();

    // matvec: wave (r,c)-quadrant: rows (wave>>1)*16..+15, cols (wave&1)*32..+31
    const int row0 = (wave >> 1) * 16;
    const int ctb = (wave & 1) * 2;       // first of 2 col-tiles
    const int arow = row0 + (lane & 15);
    const int am = lane >> 4;             // k-sub within tile

    f32x4 acc[2] = {};
#pragma unroll
    for (int kt = 0; kt < 2; ++kt) {
        bf16x8 ah = *(const bf16x8*)&tl[arow][kt * 16 + 4 * am];
#pragma unroll
        for (int c = 0; c < 2; ++c) {
            const size_t wo = ((size_t)(kt * 4 + ctb + c) * 64 + lane) * 8;
            bf16x8 wh = *(const bf16x8*)(Wh + wo);
            bf16x8 wl = *(const bf16x8*)(Wl + wo);
            acc[c] = __builtin_amdgcn_mfma_f32_16x16x32_bf16(ah, wh, acc[c], 0, 0, 0);
            acc[c] = __builtin_amdgcn_mfma_f32_16x16x32_bf16(ah, wl, acc[c], 0, 0, 0);
        }
    }

    const int rb = row0 + (lane >> 4) * 4;
    const int cb = lane & 15;
#pragma unroll
    for (int i = 0; i < 4; ++i) {
        int gnode = blockIdx.x * 32 + rb + i;
        if (gnode < N) {
            float d2 = dinv[gnode];
#pragma unroll
            for (int c = 0; c < 2; ++c)
                tout[(size_t)gnode * HID + (ctb + c) * 16 + cb] = f2bf(d2 * acc[c][i]);
        }
    }
}

// ---- plain aggregation (final layer): out = di*acc + b, bf16 ------------

__global__ void k_agg(const unsigned short* __restrict__ tin,
                      unsigned short* __restrict__ out,
                      const int* __restrict__ rs, const int* __restrict__ deg,
                      const int* __restrict__ col,
                      const float* __restrict__ dinv, const float* __restrict__ bias,
                      int N) {
    int node = (blockIdx.x * blockDim.x + threadIdx.x) >> 3;
    int l = threadIdx.x & 7;
    if (node >= N) return;
    int lane = threadIdx.x & 63;
    float di = dinv[node];
    uint4 tb = ((const uint4*)(tin + (size_t)node * HID))[l];
    float a0 = bflo(tb.x), a1 = bfhi(tb.x);
    float a2 = bflo(tb.y), a3 = bfhi(tb.y);
    float a4 = bflo(tb.z), a5 = bfhi(tb.z);
    float a6 = bflo(tb.w), a7 = bfhi(tb.w);

    int beg = rs[node];
    int cnt = deg[node];
    int last = beg + cnt - 1;
    const int gbase = lane & 56;
    for (int e = 0; e < cnt; e += NU) {
        int idx = beg + e + l;
        int cv = col[idx < last ? idx : last];
        int sv[NU];
#pragma unroll
        for (int j = 0; j < NU; j++) sv[j] = __shfl(cv, gbase + j, 64);
        uint4 vv[NU];
#pragma unroll
        for (int j = 0; j < NU; j++) vv[j] = ((const uint4*)(tin + (size_t)sv[j] * HID))[l];
#pragma unroll
        for (int j = 0; j < NU; j++) {
            a0 += bflo(vv[j].x); a1 += bfhi(vv[j].x);
            a2 += bflo(vv[j].y); a3 += bfhi(vv[j].y);
            a4 += bflo(vv[j].z); a5 += bfhi(vv[j].z);
            a6 += bflo(vv[j].w); a7 += bfhi(vv[j].w);
        }
    }
    int pad = (NU - (cnt & (NU - 1))) & (NU - 1);
    if (cnt > 0 && pad > 0) {
        float fp = (float)pad;
        uint4 vl = ((const uint4*)(tin + (size_t)col[last] * HID))[l];  // L1 hit
        a0 = fmaf(-fp, bflo(vl.x), a0); a1 = fmaf(-fp, bfhi(vl.x), a1);
        a2 = fmaf(-fp, bflo(vl.y), a2); a3 = fmaf(-fp, bfhi(vl.y), a3);
        a4 = fmaf(-fp, bflo(vl.z), a4); a5 = fmaf(-fp, bfhi(vl.z), a5);
        a6 = fmaf(-fp, bflo(vl.w), a6); a7 = fmaf(-fp, bfhi(vl.w), a7);
    }
    float4 b0 = ((const float4*)bias)[2 * l];
    float4 b1 = ((const float4*)bias)[2 * l + 1];
    a0 = fmaf(di, a0, b0.x); a1 = fmaf(di, a1, b0.y);
    a2 = fmaf(di, a2, b0.z); a3 = fmaf(di, a3, b0.w);
    a4 = fmaf(di, a4, b1.x); a5 = fmaf(di, a5, b1.y);
    a6 = fmaf(di, a6, b1.z); a7 = fmaf(di, a7, b1.w);
    uint4 o;
    o.x = pack2bf(a0, a1); o.y = pack2bf(a2, a3);
    o.z = pack2bf(a4, a5); o.w = pack2bf(a6, a7);
    ((uint4*)(out + (size_t)node * HID))[l] = o;
}

// ---- fused mean-pool + centroid-distance head (bf16 input) --------------

__global__ void k_pool_head(const unsigned short* __restrict__ h,
                            const int* __restrict__ batch,
                            const float* __restrict__ cent, const float* __restrict__ rbias,
                            float* __restrict__ out, int N) {
    int g = blockIdx.x;
    int lo = 0, hi = N;
    while (lo < hi) { int mid = (lo + hi) >> 1; if (batch[mid] < g) lo = mid + 1; else hi = mid; }
    int s = lo;
    lo = 0; hi = N;
    while (lo < hi) { int mid = (lo + hi) >> 1; if (batch[mid] < g + 1) lo = mid + 1; else hi = mid; }
    int e = lo;

    __shared__ float part[4][HID];
    __shared__ float embS[HID];
    __shared__ float dS[NCENTS];
    __shared__ float dpcS[NCLS];

    int lane = threadIdx.x & 63, wid = threadIdx.x >> 6;
    float acc = 0.0f;
    for (int i = s + wid; i < e; i += 4) acc += bf2f(h[(size_t)i * HID + lane]);
    part[wid][lane] = acc;
    __syncthreads();
    if (wid == 0) {
        float v = part[0][lane] + part[1][lane] + part[2][lane] + part[3][lane];
        embS[lane] = v / fmaxf((float)(e - s), 1.0f);
    }
    __syncthreads();
    if (threadIdx.x < NCENTS) {
        const float* c = cent + threadIdx.x * HID;
        float d = 0.0f;
        for (int k = 0; k < HID; k++) { float df = embS[k] - c[k]; d = fmaf(df, df, d); }
        dS[threadIdx.x] = d;
    }
    __syncthreads();
    if (threadIdx.x < NCLS) {
        float m = fminf(dS[threadIdx.x * 3],
                        fminf(dS[threadIdx.x * 3 + 1], dS[threadIdx.x * 3 + 2]));
        dpcS[threadIdx.x] = m;
        out[g * (NCLS + 1) + threadIdx.x] = -m;
    }
    __syncthreads();
    if (threadIdx.x == 0) {
        float m = dpcS[0];
        for (int i = 1; i < NCLS; i++) m = fminf(m, dpcS[i]);
        out[g * (NCLS + 1) + NCLS] = m - rbias[0];
    }
}

// ---- launch -------------------------------------------------------------

extern "C" void kernel_launch(void* const* d_in, const int* in_sizes, int n_in,
                              void* d_out, int out_size, void* d_ws, size_t ws_size,
                              hipStream_t stream) {
    const float* x    = (const float*)d_in[0];
    const int*   ei   = (const int*)d_in[1];   // [2, E]: row0 = src, row1 = dst
    const int*   bat  = (const int*)d_in[2];
    const float* W1   = (const float*)d_in[3];
    const float* b1   = (const float*)d_in[4];
    const float* W2   = (const float*)d_in[5];
    const float* b2   = (const float*)d_in[6];
    const float* W3   = (const float*)d_in[7];
    const float* b3   = (const float*)d_in[8];
    const float* cent = (const float*)d_in[9];
    const float* rb   = (const float*)d_in[10];
    float* out = (float*)d_out;

    const int N = in_sizes[0] / 128;
    const int E = in_sizes[1] / 2;
    const int nbins = (N + BINW - 1) >> BSHIFT;

    char* p = (char*)d_ws;
    unsigned short* T0 = (unsigned short*)p; p += (size_t)N * HID * 2;  // bf16 gather table
    unsigned short* T1 = (unsigned short*)p; p += (size_t)N * HID * 2;  // bf16 gather table
    int2*  binned = (int2*)p;  p += (size_t)E * 8;
    int*   col    = (int*)p;   p += (size_t)E * 4;
    float* dinv   = (float*)p; p += (size_t)N * 4;
    int*   rs     = (int*)p;   p += (size_t)N * 4;
    int*   deg    = (int*)p;   p += (size_t)N * 4;
    int*   binBase= (int*)p;   p += (NBINMAX + 2) * 4;
    // zeroed region: binCnt | binCur
    int*   binCnt = (int*)p;   p += NBINMAX * 4;
    int*   binCur = (int*)p;   p += NBINMAX * 4;
    p = (char*)(((uintptr_t)p + 15) & ~(uintptr_t)15);
    unsigned short* W1h = (unsigned short*)p; p += 8192 * 2;
    unsigned short* W1l = (unsigned short*)p; p += 8192 * 2;
    unsigned short* W2h = (unsigned short*)p; p += 4096 * 2;
    unsigned short* W2l = (unsigned short*)p; p += 4096 * 2;
    unsigned short* W3h = (unsigned short*)p; p += 4096 * 2;
    unsigned short* W3l = (unsigned short*)p; p += 4096 * 2;

    hipMemsetAsync(binCnt, 0, 2 * NBINMAX * 4, stream);

    const int nEB = ceil_div(E, CHUNK);
    k_count_w<<<nEB + 3, 256, 0, stream>>>(ei + E, binCnt, E, nbins,
                                           W1, W2, W3, W1h, W1l, W2h, W2l, W3h, W3l);
    k_binoff<<<1, 256, 0, stream>>>(binCnt, binBase, nbins, E);
    k_bin<<<nEB, 256, 0, stream>>>(ei, ei + E, binBase, binCur, binned, E, nbins);
    k_fillc2<<<nbins, 256, 0, stream>>>(binned, binBase, col, rs, deg, dinv, N);

    k_gemm_mfma<128><<<ceil_div(N, 64), 256, 0, stream>>>(x, W1h, W1l, T0, dinv, N);
    k_aggf<<<ceil_div(N, 32), 256, 0, stream>>>(T0, T1, rs, deg, col, dinv, b1, W2h, W2l, N);
    k_aggf<<<ceil_div(N, 32), 256, 0, stream>>>(T1, T0, rs, deg, col, dinv, b2, W3h, W3l, N);
    k_agg<<<ceil_div(N * 8, 256), 256, 0, stream>>>(T0, T1, rs, deg, col, dinv, b3, N);

    k_pool_head<<<1024, 256, 0, stream>>>(T1, bat, cent, rb, out, N);
}